// Round 11
// baseline (236.348 us; speedup 1.0000x reference)
//
#include <hip/hip_runtime.h>
#include <math.h>

#define BN 32
#define LL 1024
#define HH 128

typedef __attribute__((ext_vector_type(8))) short short8;
typedef __attribute__((ext_vector_type(4))) float f32x4;

static const size_t SZ_BF = (size_t)BN * LL * HH * 2;  // one bf16 matrix = 8 MB

__device__ __forceinline__ ushort f2bf(float x) {
  union { float f; unsigned u; } c; c.f = x;
  unsigned r = c.u + 0x7fffu + ((c.u >> 16) & 1u);
  return (ushort)(r >> 16);
}
__device__ __forceinline__ float bf2f(ushort h) {
  union { unsigned u; float f; } c; c.u = ((unsigned)h) << 16;
  return c.f;
}
__device__ __forceinline__ short8 ld8(const ushort* p) {
  return *(const short8*)p;
}

// ---------------------------------------------------------------------------
// k_convert: f32 -> bf16 copies a,b + transposed aT,bT + fused means.
// 1-D grid 1024, bb = wg&31 -> XCD-pinned per batch so the bf16 corpus is
// written into the same XCD L2 that colsum/features will read it from.
// ---------------------------------------------------------------------------
__global__ __launch_bounds__(256) void k_convert(
    const float* __restrict__ a, const float* __restrict__ b,
    const int* __restrict__ mask_b,
    ushort* __restrict__ abf, ushort* __restrict__ bbf,
    ushort* __restrict__ aT, ushort* __restrict__ bT,
    float* __restrict__ meanb, float* __restrict__ invmean) {
  int wg = blockIdx.x;
  int bb = wg & 31;
  int rest = wg >> 5;                  // 0..31
  int which = rest & 1;                // 0 -> a (->invmean), 1 -> b (->meanb)
  int l0 = (rest >> 1) * 64;
  const float* src = which ? b : a;
  ushort* dst  = which ? bbf : abf;
  ushort* dstT = which ? bT : aT;
  float* dmean = which ? meanb : invmean;
  __shared__ __align__(16) ushort T[128][72];  // [d][l], padded
  __shared__ float accS[128];
  __shared__ float wgt[64];
  int t = threadIdx.x;
  if (t < 128) accS[t] = 0.f;
  if (t < 64)
    wgt[t] = which ? 1.0f : ((mask_b[bb * LL + l0 + t] == 0) ? 1.0f : 0.0f);
  int lrow = t >> 5;         // 0..7
  int dcol = (t & 31) * 4;   // 0..124
#pragma unroll
  for (int p = 0; p < 8; ++p) {
    int l = p * 8 + lrow;
    float4 v = *(const float4*)&src[((size_t)bb * LL + l0 + l) * HH + dcol];
    ushort4 u;
    u.x = f2bf(v.x); u.y = f2bf(v.y); u.z = f2bf(v.z); u.w = f2bf(v.w);
    *(ushort4*)&dst[((size_t)bb * LL + l0 + l) * HH + dcol] = u;
    T[dcol + 0][l] = u.x; T[dcol + 1][l] = u.y;
    T[dcol + 2][l] = u.z; T[dcol + 3][l] = u.w;
  }
  __syncthreads();
  int drow = t >> 3;        // 0..31
  int c8 = (t & 7) * 8;     // 0..56
#pragma unroll
  for (int q = 0; q < 4; ++q) {
    int d = q * 32 + drow;
    short8 val = *(const short8*)&T[d][c8];
    *(short8*)&dstT[((size_t)bb * HH + d) * LL + l0 + c8] = val;
    float s = 0.f;
#pragma unroll
    for (int j = 0; j < 8; ++j) s += wgt[c8 + j] * bf2f((ushort)val[j]);
    atomicAdd(&accS[d], s);
  }
  __syncthreads();
  if (t < 128) atomicAdd(&dmean[bb * HH + t], accS[t]);
}

// ---------------------------------------------------------------------------
// k_colsum v6: computes e[l][m] = exp(s*temp + biasA + biasB) tile-by-tile,
// MATERIALIZES e (bf16, l-major) to global, accumulates colsum[m], writes
// invc[b][m] (0 if sum==0).  1-D grid 1024, bb = wg&31 (XCD-pinned).
// Block = 32 m; waves split the l-sweep; Al prefetched one iter ahead.
// e stores are fire-and-forget scalar b16 (32 B segments, merged in L2).
// ---------------------------------------------------------------------------
__global__ __launch_bounds__(256, 4) void k_colsum(
    const ushort* __restrict__ abf, const ushort* __restrict__ bbf,
    const int* __restrict__ mask_a, const int* __restrict__ mask_b,
    const float* __restrict__ temp_p, float* __restrict__ invc,
    ushort* __restrict__ eg) {
  int wg = blockIdx.x;
  int bb = wg & 31;
  int m0 = (wg >> 5) * 32;
  int t = threadIdx.x;
  int w = t >> 6, lane = t & 63, l16 = lane & 15, quad = lane >> 4;
  float temp = temp_p[0];
  __shared__ float biasA[LL];
  __shared__ float csred[4][2][16];
  for (int i = t; i < LL; i += 256)
    biasA[i] = mask_a[bb * LL + i] ? 0.0f : -10000.0f;

  short8 Bm[2][4];
  float biasB[2];
#pragma unroll
  for (int mt = 0; mt < 2; ++mt) {
    int m = m0 + mt * 16 + l16;
    biasB[mt] = mask_b[bb * LL + m] ? 0.0f : -10000.0f;
#pragma unroll
    for (int k = 0; k < 4; ++k)
      Bm[mt][k] = ld8(&bbf[((size_t)bb * LL + m) * HH + k * 32 + quad * 8]);
  }
  __syncthreads();

  short8 Al[4];
  {
    const ushort* arow = &abf[((size_t)bb * LL + w * 256 + l16) * HH];
#pragma unroll
    for (int k = 0; k < 4; ++k) Al[k] = ld8(&arow[k * 32 + quad * 8]);
  }
  float cs[2] = {0.f, 0.f};
  for (int it = 0; it < 16; ++it) {
    int lbase = w * 256 + it * 16;
    short8 AlN[4];
    {
      int itn = (it + 1) & 15;
      const ushort* arow = &abf[((size_t)bb * LL + w * 256 + itn * 16 + l16) * HH];
#pragma unroll
      for (int k = 0; k < 4; ++k) AlN[k] = ld8(&arow[k * 32 + quad * 8]);
    }
#pragma unroll
    for (int mt = 0; mt < 2; ++mt) {
      f32x4 sacc = {0.f, 0.f, 0.f, 0.f};
#pragma unroll
      for (int k = 0; k < 4; ++k)
        sacc = __builtin_amdgcn_mfma_f32_16x16x32_bf16(Al[k], Bm[mt][k], sacc, 0, 0, 0);
#pragma unroll
      for (int r = 0; r < 4; ++r) {
        int l = lbase + quad * 4 + r;   // D row = l; col = m = m0+mt*16+l16
        float ev = __expf(sacc[r] * temp + biasA[l] + biasB[mt]);
        cs[mt] += ev;
        eg[((size_t)bb * LL + l) * LL + m0 + mt * 16 + l16] = f2bf(ev);
      }
    }
#pragma unroll
    for (int k = 0; k < 4; ++k) Al[k] = AlN[k];
  }
#pragma unroll
  for (int mt = 0; mt < 2; ++mt) {
    cs[mt] += __shfl_xor(cs[mt], 16);
    cs[mt] += __shfl_xor(cs[mt], 32);
  }
  if (lane < 16) {
#pragma unroll
    for (int mt = 0; mt < 2; ++mt) csred[w][mt][l16] = cs[mt];
  }
  __syncthreads();
  if (t < 32) {
    float s = csred[0][t >> 4][t & 15] + csred[1][t >> 4][t & 15] +
              csred[2][t >> 4][t & 15] + csred[3][t >> 4][t & 15];
    invc[bb * LL + m0 + t] = s > 0.f ? 1.0f / s : 0.0f;
  }
}

// ---------------------------------------------------------------------------
// k_scale: aT[d][m] *= invc[m] in place (aT -> aS).  1-D grid 2048,
// bb = wg&31 (XCD-pinned so aS lands in the right L2); coalesced ushort8.
// ---------------------------------------------------------------------------
__global__ __launch_bounds__(256) void k_scale(
    ushort* __restrict__ aT, const float* __restrict__ invc) {
  int wg = blockIdx.x;
  int bb = wg & 31;
  int ch = wg >> 5;                    // 0..63 chunk within batch
  size_t base = ((size_t)bb << 17) + (size_t)ch * 2048 + (size_t)threadIdx.x * 8;
  int m = (int)(base & (LL - 1));
  short8 v = *(short8*)&aT[base];
  float4 i0 = *(const float4*)&invc[bb * LL + m];
  float4 i1 = *(const float4*)&invc[bb * LL + m + 4];
  short8 o;
  o[0] = (short)f2bf(bf2f((ushort)v[0]) * i0.x);
  o[1] = (short)f2bf(bf2f((ushort)v[1]) * i0.y);
  o[2] = (short)f2bf(bf2f((ushort)v[2]) * i0.z);
  o[3] = (short)f2bf(bf2f((ushort)v[3]) * i0.w);
  o[4] = (short)f2bf(bf2f((ushort)v[4]) * i1.x);
  o[5] = (short)f2bf(bf2f((ushort)v[5]) * i1.y);
  o[6] = (short)f2bf(bf2f((ushort)v[6]) * i1.z);
  o[7] = (short)f2bf(bf2f((ushort)v[7]) * i1.w);
  *(short8*)&aT[base] = o;
}

// ---------------------------------------------------------------------------
// k_features v7: PURE dual-GEMM over materialized e — no S-phase, no exp,
// no LDS, NO BARRIER in the loop.  1-D grid 1024 (32 l-rows/block, 4/CU),
// bb = wg&31.  Waves split d (w*32).  Per 64-m iter: 4 Pa-frag loads from e
// (A-operand, rows l), 8 bT/aS B-frag loads, 12 MFMAs:
//   accA += Pa@bT, accB += Pa@aS, accR += Pa@ones (rowsum, lane-aligned).
// Epilogue: fa = rowsum>0 ? accA/rowsum : mean(b); fb = accB + invmean/1024.
// ~110 VGPR incl. acc -> 4 waves/SIMD; wave-level overlap hides load latency.
// ---------------------------------------------------------------------------
__global__ __launch_bounds__(256, 4) void k_features(
    const ushort* __restrict__ eg, const ushort* __restrict__ aS,
    const ushort* __restrict__ bT, const float* __restrict__ meanb,
    const float* __restrict__ invmean, float* __restrict__ out) {
  int wg = blockIdx.x;
  int bb = wg & 31;
  int l0 = (wg >> 5) * 32;
  int t = threadIdx.x;
  int w = t >> 6, lane = t & 63, l16 = lane & 15, quad = lane >> 4;

  short8 Bones;
#pragma unroll
  for (int j = 0; j < 8; ++j) Bones[j] = (short)0x3F80;  // bf16 1.0

  f32x4 accA[2][2], accB[2][2], accR[2];
  f32x4 zero = {0.f, 0.f, 0.f, 0.f};
#pragma unroll
  for (int lt = 0; lt < 2; ++lt) {
    accR[lt] = zero;
#pragma unroll
    for (int dt = 0; dt < 2; ++dt) { accA[lt][dt] = zero; accB[lt][dt] = zero; }
  }

  const ushort* erow0 = &eg[((size_t)bb * LL + l0 + l16) * LL + quad * 8];
  const ushort* erow1 = erow0 + 16 * LL;

  for (int m0 = 0; m0 < LL; m0 += 64) {
    // Pa A-frags first (longest latency: e may be L3/HBM on first touch)
    short8 Pa[2][2];
#pragma unroll
    for (int ks = 0; ks < 2; ++ks) {
      Pa[0][ks] = ld8(erow0 + m0 + ks * 32);
      Pa[1][ks] = ld8(erow1 + m0 + ks * 32);
    }
    short8 Bb[2][2], Bs[2][2];
#pragma unroll
    for (int dt = 0; dt < 2; ++dt) {
      size_t drow = (size_t)bb * HH + w * 32 + dt * 16 + l16;
      const ushort* btrow = &bT[drow * LL + m0];
      const ushort* asrow = &aS[drow * LL + m0];
#pragma unroll
      for (int ks = 0; ks < 2; ++ks) {
        Bb[dt][ks] = ld8(&btrow[ks * 32 + quad * 8]);
        Bs[dt][ks] = ld8(&asrow[ks * 32 + quad * 8]);
      }
    }
#pragma unroll
    for (int lt = 0; lt < 2; ++lt) {
#pragma unroll
      for (int ks = 0; ks < 2; ++ks) {
        accR[lt] = __builtin_amdgcn_mfma_f32_16x16x32_bf16(Pa[lt][ks], Bones, accR[lt], 0, 0, 0);
#pragma unroll
        for (int dt = 0; dt < 2; ++dt) {
          accA[lt][dt] = __builtin_amdgcn_mfma_f32_16x16x32_bf16(Pa[lt][ks], Bb[dt][ks], accA[lt][dt], 0, 0, 0);
          accB[lt][dt] = __builtin_amdgcn_mfma_f32_16x16x32_bf16(Pa[lt][ks], Bs[dt][ks], accB[lt][dt], 0, 0, 0);
        }
      }
    }
  }

  // epilogue — accR row l lives in slot r exactly like accA/accB rows
  float* outA = out;
  float* outB = out + (size_t)BN * LL * HH;
#pragma unroll
  for (int dt = 0; dt < 2; ++dt) {
    int d = w * 32 + dt * 16 + l16;
    float mb = meanb[bb * HH + d] * (1.0f / 1024.0f);
    float im = invmean[bb * HH + d] * (1.0f / 1024.0f);
#pragma unroll
    for (int lt = 0; lt < 2; ++lt) {
#pragma unroll
      for (int r = 0; r < 4; ++r) {
        int l = l0 + lt * 16 + quad * 4 + r;
        float rsv = accR[lt][r];
        float fa = (rsv > 0.f) ? accA[lt][dt][r] / rsv : mb;
        float fb = accB[lt][dt][r] + im;
        outA[((size_t)bb * LL + l) * HH + d] = fa;
        outB[((size_t)bb * LL + l) * HH + d] = fb;
      }
    }
  }
}

// ---------------------------------------------------------------------------
extern "C" void kernel_launch(void* const* d_in, const int* in_sizes, int n_in,
                              void* d_out, int out_size, void* d_ws, size_t ws_size,
                              hipStream_t stream) {
  const float* a = (const float*)d_in[0];
  const float* b = (const float*)d_in[1];
  const int* mask_a = (const int*)d_in[2];
  const int* mask_b = (const int*)d_in[3];
  const float* temp = (const float*)d_in[4];
  float* out = (float*)d_out;

  char* wsb = (char*)d_ws;
  ushort* abf = (ushort*)(wsb + 0 * SZ_BF);
  ushort* bbf = (ushort*)(wsb + 1 * SZ_BF);
  ushort* aT  = (ushort*)(wsb + 2 * SZ_BF);   // becomes aS after k_scale
  ushort* bT  = (ushort*)(wsb + 3 * SZ_BF);
  float* invc = (float*)(wsb + 4 * SZ_BF);                 // 128 KB
  float* meanb   = invc + (size_t)BN * LL;                 // 16 KB
  float* invmean = meanb + BN * HH;                        // 16 KB
  ushort* eg = (ushort*)(wsb + 4 * SZ_BF + 256 * 1024);    // 64 MB e matrix

  hipMemsetAsync(meanb, 0, 2 * BN * HH * sizeof(float), stream);
  k_convert<<<dim3(1024), 256, 0, stream>>>(a, b, mask_b, abf, bbf, aT, bT,
                                            meanb, invmean);
  k_colsum<<<dim3(1024), 256, 0, stream>>>(abf, bbf, mask_a, mask_b, temp,
                                           invc, eg);
  k_scale<<<dim3(2048), 256, 0, stream>>>(aT, invc);
  k_features<<<dim3(1024), 256, 0, stream>>>(eg, aT, bT, meanb, invmean, out);
  (void)in_sizes; (void)n_in; (void)out_size; (void)ws_size;
}